// Round 7
// baseline (106.436 us; speedup 1.0000x reference)
//
#include <hip/hip_runtime.h>

// InfoNCE loss, round 7: single fused dispatch.
// Each block computes one row's partial loss; last-finishing block
// (device-scope counter) reduces all 2048 partials and writes out[0].
// Deterministic: reduction order fixed; only the int counter is atomic.

constexpr int BATCH = 2048;
constexpr int DIM   = 128;
constexpr int N_NEG = 63;
constexpr float TEMP_INV = 1.0f / 0.07f;
constexpr float EPSF = 1e-12f;

typedef float v4f __attribute__((ext_vector_type(4)));

__global__ __launch_bounds__(512) void infonce_fused(
    const float* __restrict__ q,       // [BATCH][DIM]
    const float* __restrict__ r,       // [VOCAB][DIM]
    const int*   __restrict__ pos,     // [BATCH]
    const int*   __restrict__ neg,     // [BATCH][N_NEG]
    float* __restrict__ partial,       // [BATCH] (d_ws)
    unsigned* __restrict__ counter,    // [1] (d_ws), zeroed per launch
    float* __restrict__ out)           // [1]
{
    const int b   = blockIdx.x;          // one batch row per block
    const int tid = threadIdx.x;         // 0..511
    const int c   = tid >> 3;            // candidate 0..63 (0 = positive)
    const int t   = tid & 7;             // sub-lane within candidate

    int idx = (c == 0) ? pos[b] : neg[(size_t)b * N_NEG + (c - 1)];

    const v4f* rrow = reinterpret_cast<const v4f*>(r + (size_t)idx * DIM);
    const v4f* qrow = reinterpret_cast<const v4f*>(q + (size_t)b * DIM);

    // Load everything first (8 independent 16B loads), compute after.
    // r-rows: non-temporal (no L1 reuse on a random 51MB gather).
    v4f rv[4], qv[4];
    #pragma unroll
    for (int j = 0; j < 4; ++j) rv[j] = __builtin_nontemporal_load(&rrow[t + 8 * j]);
    #pragma unroll
    for (int j = 0; j < 4; ++j) qv[j] = qrow[t + 8 * j];

    float dot = 0.0f, rn = 0.0f, qn = 0.0f;
    #pragma unroll
    for (int j = 0; j < 4; ++j) {
        dot += qv[j].x * rv[j].x + qv[j].y * rv[j].y + qv[j].z * rv[j].z + qv[j].w * rv[j].w;
        rn  += rv[j].x * rv[j].x + rv[j].y * rv[j].y + rv[j].z * rv[j].z + rv[j].w * rv[j].w;
        qn  += qv[j].x * qv[j].x + qv[j].y * qv[j].y + qv[j].z * qv[j].z + qv[j].w * qv[j].w;
    }

    // reduce dot, rn, qn over the 8-lane candidate group (aligned within wave)
    #pragma unroll
    for (int d = 1; d <= 4; d <<= 1) {
        dot += __shfl_xor(dot, d, 64);
        rn  += __shfl_xor(rn,  d, 64);
        qn  += __shfl_xor(qn,  d, 64);
    }

    float qnorm = fmaxf(sqrtf(qn), EPSF);
    float rnorm = fmaxf(sqrtf(rn), EPSF);
    float s = dot / (qnorm * rnorm) * TEMP_INV;   // score for candidate c

    __shared__ float sv[64];
    if (t == 0) sv[c] = s;
    __syncthreads();

    // wave 0: 64-way logsumexp -> per-row partial
    if (tid < 64) {
        float x = sv[tid];
        float m = x;
        #pragma unroll
        for (int d = 32; d >= 1; d >>= 1) m = fmaxf(m, __shfl_xor(m, d, 64));
        float e = __expf(x - m);
        #pragma unroll
        for (int d = 32; d >= 1; d >>= 1) e += __shfl_xor(e, d, 64);
        if (tid == 0) {
            float lse = m + __logf(e);
            partial[b] = lse - sv[0];          // un-normalized per-row loss
        }
    }

    // --- last block reduces all partials ---
    __shared__ bool amLast;
    if (tid == 0) {
        __threadfence();                               // release partial[b]
        unsigned prev = atomicAdd(counter, 1u);        // device-scope
        amLast = (prev == (unsigned)(gridDim.x - 1));
    }
    __syncthreads();

    if (amLast) {
        __threadfence();                               // acquire others' partials
        // 2048 floats = 512 contiguous float4, one per thread
        v4f v = reinterpret_cast<const v4f*>(partial)[tid];
        float s2 = v.x + v.y + v.z + v.w;
        #pragma unroll
        for (int d = 32; d >= 1; d >>= 1) s2 += __shfl_xor(s2, d, 64);

        __shared__ float wsum[8];
        if ((tid & 63) == 0) wsum[tid >> 6] = s2;
        __syncthreads();
        if (tid == 0) {
            float tot = 0.0f;
            #pragma unroll
            for (int w = 0; w < 8; ++w) tot += wsum[w];
            out[0] = tot * (1.0f / (float)BATCH);
        }
    }
}

extern "C" void kernel_launch(void* const* d_in, const int* in_sizes, int n_in,
                              void* d_out, int out_size, void* d_ws, size_t ws_size,
                              hipStream_t stream) {
    const float* q   = (const float*)d_in[0];
    const float* r   = (const float*)d_in[1];
    const int*   pos = (const int*)d_in[2];
    const int*   neg = (const int*)d_in[3];
    float* out       = (float*)d_out;
    float* partial   = (float*)d_ws;                       // 2048 floats
    unsigned* counter = (unsigned*)((char*)d_ws + BATCH * sizeof(float));

    hipMemsetAsync(counter, 0, sizeof(unsigned), stream);  // tiny front node
    infonce_fused<<<dim3(BATCH), dim3(512), 0, stream>>>(q, r, pos, neg,
                                                         partial, counter, out);
}

// Round 8
// 16.802 us; speedup vs baseline: 6.3349x; 6.3349x over previous
//
#include <hip/hip_runtime.h>

// InfoNCE loss, round 8: revert to round-6 two-dispatch structure
// (round 7's fused version: per-block device-scope fences -> L2 writeback
// storms across 8 XCDs, 111 us. Never again.)
// Change vs round 6: reduce kernel is a single 64-lane wave, 8 float4
// loads in flight per lane, shuffle-reduce, no LDS/sync.

constexpr int BATCH = 2048;
constexpr int DIM   = 128;
constexpr int N_NEG = 63;
constexpr float TEMP_INV = 1.0f / 0.07f;
constexpr float EPSF = 1e-12f;

typedef float v4f __attribute__((ext_vector_type(4)));

__global__ __launch_bounds__(512) void infonce_partial(
    const float* __restrict__ q,       // [BATCH][DIM]
    const float* __restrict__ r,       // [VOCAB][DIM]
    const int*   __restrict__ pos,     // [BATCH]
    const int*   __restrict__ neg,     // [BATCH][N_NEG]
    float* __restrict__ partial)       // [BATCH]
{
    const int b   = blockIdx.x;          // one batch row per block
    const int tid = threadIdx.x;         // 0..511
    const int c   = tid >> 3;            // candidate 0..63 (0 = positive)
    const int t   = tid & 7;             // sub-lane within candidate

    int idx = (c == 0) ? pos[b] : neg[(size_t)b * N_NEG + (c - 1)];

    const v4f* rrow = reinterpret_cast<const v4f*>(r + (size_t)idx * DIM);
    const v4f* qrow = reinterpret_cast<const v4f*>(q + (size_t)b * DIM);

    // Load everything first (8 independent 16B loads), compute after.
    // r-rows: non-temporal (random 51MB gather, no L1 reuse).
    v4f rv[4], qv[4];
    #pragma unroll
    for (int j = 0; j < 4; ++j) rv[j] = __builtin_nontemporal_load(&rrow[t + 8 * j]);
    #pragma unroll
    for (int j = 0; j < 4; ++j) qv[j] = qrow[t + 8 * j];

    float dot = 0.0f, rn = 0.0f, qn = 0.0f;
    #pragma unroll
    for (int j = 0; j < 4; ++j) {
        dot += qv[j].x * rv[j].x + qv[j].y * rv[j].y + qv[j].z * rv[j].z + qv[j].w * rv[j].w;
        rn  += rv[j].x * rv[j].x + rv[j].y * rv[j].y + rv[j].z * rv[j].z + rv[j].w * rv[j].w;
        qn  += qv[j].x * qv[j].x + qv[j].y * qv[j].y + qv[j].z * qv[j].z + qv[j].w * qv[j].w;
    }

    // reduce dot, rn, qn over the 8-lane candidate group (aligned within wave)
    #pragma unroll
    for (int d = 1; d <= 4; d <<= 1) {
        dot += __shfl_xor(dot, d, 64);
        rn  += __shfl_xor(rn,  d, 64);
        qn  += __shfl_xor(qn,  d, 64);
    }

    float qnorm = fmaxf(sqrtf(qn), EPSF);
    float rnorm = fmaxf(sqrtf(rn), EPSF);
    float s = dot / (qnorm * rnorm) * TEMP_INV;   // score for candidate c

    __shared__ float sv[64];
    if (t == 0) sv[c] = s;
    __syncthreads();

    // wave 0 does the 64-way logsumexp and stores the per-row partial
    if (tid < 64) {
        float x = sv[tid];
        float m = x;
        #pragma unroll
        for (int d = 32; d >= 1; d >>= 1) m = fmaxf(m, __shfl_xor(m, d, 64));
        float e = __expf(x - m);
        #pragma unroll
        for (int d = 32; d >= 1; d >>= 1) e += __shfl_xor(e, d, 64);
        if (tid == 0) {
            float lse = m + __logf(e);
            partial[b] = lse - sv[0];          // un-normalized per-row loss
        }
    }
}

__global__ __launch_bounds__(64) void infonce_reduce(
    const float* __restrict__ partial,   // [BATCH]
    float* __restrict__ out)             // [1]
{
    const int lane = threadIdx.x;        // 0..63, one wave
    const v4f* p4 = reinterpret_cast<const v4f*>(partial);

    // 2048 floats = 512 float4; lane reads 8 float4 (all in flight)
    v4f v[8];
    #pragma unroll
    for (int j = 0; j < 8; ++j) v[j] = p4[lane + 64 * j];

    float s = 0.0f;
    #pragma unroll
    for (int j = 0; j < 8; ++j) s += v[j].x + v[j].y + v[j].z + v[j].w;

    #pragma unroll
    for (int d = 32; d >= 1; d >>= 1) s += __shfl_xor(s, d, 64);

    if (lane == 0) out[0] = s * (1.0f / (float)BATCH);
}

extern "C" void kernel_launch(void* const* d_in, const int* in_sizes, int n_in,
                              void* d_out, int out_size, void* d_ws, size_t ws_size,
                              hipStream_t stream) {
    const float* q   = (const float*)d_in[0];
    const float* r   = (const float*)d_in[1];
    const int*   pos = (const int*)d_in[2];
    const int*   neg = (const int*)d_in[3];
    float* out     = (float*)d_out;
    float* partial = (float*)d_ws;       // 2048 floats, fully rewritten each call

    infonce_partial<<<dim3(BATCH), dim3(512), 0, stream>>>(q, r, pos, neg, partial);
    infonce_reduce<<<dim3(1), dim3(64), 0, stream>>>(partial, out);
}